// Round 2
// baseline (507.150 us; speedup 1.0000x reference)
//
#include <hip/hip_runtime.h>
#include <hip/hip_bf16.h>

#define N_NODES 100000
#define N_EDGES 1600000
#define OUTF 128
#define INF 256
#define SCAN_CHUNK 1024
#define SCAN_BLOCKS 98   // 98*1024 = 100352 >= 100000
#define M_TILES 6250     // 100000 / 16

typedef _Float16 f16;
typedef _Float16 half8 __attribute__((ext_vector_type(8)));
typedef _Float16 half4 __attribute__((ext_vector_type(4)));
typedef _Float16 half2v __attribute__((ext_vector_type(2)));
typedef float floatx4 __attribute__((ext_vector_type(4)));

// ---------------- fused degree count + edge rank (ONE atomic pass) ----------------
__global__ void count_rank_kernel(const int* __restrict__ dst, int E,
                                  int* __restrict__ deg, int* __restrict__ rank) {
    int i = blockIdx.x * blockDim.x + threadIdx.x;
    if (i < E) rank[i] = atomicAdd(&deg[dst[i]], 1);
}

// ---------------- scan step 1: per-chunk sums ----------------
__global__ __launch_bounds__(256) void scan_partial_kernel(const int* __restrict__ deg, int n,
                                                           int* __restrict__ partial) {
    __shared__ int red[256];
    int b = blockIdx.x, t = threadIdx.x;
    int base = b * SCAN_CHUNK;
    int s = 0;
    for (int i = t; i < SCAN_CHUNK; i += 256) {
        int idx = base + i;
        if (idx < n) s += deg[idx];
    }
    red[t] = s;
    __syncthreads();
    for (int off = 128; off > 0; off >>= 1) {
        if (t < off) red[t] += red[t + off];
        __syncthreads();
    }
    if (t == 0) partial[b] = red[0];
}

// ---------------- scan step 2: exclusive scan of partials (nb <= 128) ----------------
__global__ __launch_bounds__(128) void scan_top_kernel(int* __restrict__ partial, int nb,
                                                       int* __restrict__ row_start, int n) {
    __shared__ int sc[128];
    int t = threadIdx.x;
    int v = (t < nb) ? partial[t] : 0;
    sc[t] = v;
    __syncthreads();
    for (int off = 1; off < 128; off <<= 1) {
        int val = sc[t];
        int add = (t >= off) ? sc[t - off] : 0;
        __syncthreads();
        sc[t] = val + add;
        __syncthreads();
    }
    if (t < nb) partial[t] = sc[t] - v;   // exclusive
    if (t == 127) row_start[n] = sc[127]; // total edge count
}

// ---------------- scan step 3: per-chunk exclusive scan + norms ----------------
__global__ __launch_bounds__(256) void scan_final_kernel(const int* __restrict__ deg, int n,
                                                         const int* __restrict__ partial,
                                                         int* __restrict__ row_start,
                                                         float* __restrict__ norm1,
                                                         float* __restrict__ norm2) {
    __shared__ int sc[256];
    int b = blockIdx.x, t = threadIdx.x;
    int base = b * SCAN_CHUNK + t * 4;
    int v[4];
    int tsum = 0;
#pragma unroll
    for (int j = 0; j < 4; j++) {
        int idx = base + j;
        v[j] = (idx < n) ? deg[idx] : 0;
        tsum += v[j];
    }
    sc[t] = tsum;
    __syncthreads();
    for (int off = 1; off < 256; off <<= 1) {
        int val = sc[t];
        int add = (t >= off) ? sc[t - off] : 0;
        __syncthreads();
        sc[t] = val + add;
        __syncthreads();
    }
    int run = sc[t] - tsum + partial[b];
#pragma unroll
    for (int j = 0; j < 4; j++) {
        int idx = base + j;
        if (idx < n) {
            row_start[idx] = run;
            float d = (float)(v[j] > 0 ? v[j] : 1); // clip(deg, 1)
            norm1[idx] = rsqrtf(d);
            norm2[idx] = 1.0f / d;
            run += v[j];
        }
    }
}

// ---------------- edge scatter into CSR slots (atomic-free) ----------------
__global__ void scatter_edges_kernel(const int* __restrict__ src, const int* __restrict__ dst,
                                     const int* __restrict__ rank,
                                     const int* __restrict__ row_start,
                                     int E, int* __restrict__ srcs_sorted) {
    int i = blockIdx.x * blockDim.x + threadIdx.x;
    if (i < E) {
        srcs_sorted[row_start[dst[i]] + rank[i]] = src[i];
    }
}

// ---------------- convert W_mean|W_var into f16 Bt, wave-friendly layout ----------------
// Bt row ng = g*16 + i, g in [0,16): g = ch*8 + w*2 + cg
//   ch = column half (0/1), w = wave (0..3), cg: 0 -> mean, 1 -> var
// actual col = ch*64 + w*16 + i (0..127);  Bt[ng][k] = W[k][col]
__global__ __launch_bounds__(256) void convert_B_kernel(const float* __restrict__ Wm,
                                                        const float* __restrict__ Wv,
                                                        f16* __restrict__ Bt) {
    int k = threadIdx.x;
    int ng = blockIdx.x;
    int g = ng >> 4, i = ng & 15;
    int ch = g >> 3, w = (g >> 1) & 3, cg = g & 1;
    int col = ch * 64 + w * 16 + i;
    const float* srcW = cg ? Wv : Wm;
    Bt[ng * 256 + k] = (f16)srcW[k * 128 + col];
}

// ---------------- MFMA projection + relu + attention + msg (f16) ----------------
// block = 256 (4 waves). Grid = 2500: blockIdx&1 = column half, blockIdx>>1 = tile
// chunk (1250 chunks x 5 tiles grid-stride). Wave w owns 16 cols for mean & var.
//
// R1 post-mortem: VGPR_Count=48 proved the allocator sank the B loads into the
// tile loop (L2 re-fetch every tile) AND batch-serialized the 16 A loads behind
// full-latency waitcnts — 122 us with every pipe <8% busy at 51% occupancy.
// Fixes here:
//  (a) B fragments PINNED in registers via empty asm: non-sinkable, forces the
//      64-VGPR residency the heuristic refused.
//  (b) A software-prefetched one tile ahead into a 16x floatx4 reg buffer: cvt
//      consumes tile t while the 16 loads for t+1250 go in flight under the
//      MFMA+epilogue phase (reg-staged pipeline, all indices compile-time).
//  (c) __launch_bounds__(256,2): 256-VGPR cap so ~200 VGPR demand fits, 0 spill.
__global__ __launch_bounds__(256, 2) void proj_mfma_kernel(const float* __restrict__ feat,
                                                           const f16* __restrict__ Bt,
                                                           const float* __restrict__ norm1,
                                                           const float* __restrict__ norm2,
                                                           f16* __restrict__ msg) {
    int tid = threadIdx.x;
    int w = tid >> 6;
    int lane = tid & 63;
    int quad = lane >> 4;
    int l15 = lane & 15;
    int ch = blockIdx.x & 1;
    int tbase = blockIdx.x >> 1;

    // load B fragments once: 2 col-groups (mean/var, same 16 cols) x 8 k-frags
    half8 b[2][8];
#pragma unroll
    for (int cg = 0; cg < 2; cg++) {
        int g = ch * 8 + w * 2 + cg;
        const f16* bp = Bt + (size_t)(g * 16 + l15) * 256 + quad * 8;
#pragma unroll
        for (int kf = 0; kf < 8; kf++) {
            b[cg][kf] = *(const half8*)(bp + kf * 32);
        }
    }
    // pin: forces register residency across the loop (allocator can't sink/remat)
#pragma unroll
    for (int cg = 0; cg < 2; cg++) {
#pragma unroll
        for (int kf = 0; kf < 8; kf++) {
            asm volatile("" : "+v"(b[cg][kf]));
        }
    }

    int col = ch * 64 + w * 16 + l15; // 0..127
    size_t arow = (size_t)l15 * 256 + quad * 8;

    // prologue: prefetch first tile into registers
    floatx4 pf[16];
    {
        const float* ap = feat + (size_t)tbase * 16 * 256 + arow;
#pragma unroll
        for (int kf = 0; kf < 8; kf++) {
            pf[2 * kf] = *(const floatx4*)(ap + kf * 32);
            pf[2 * kf + 1] = *(const floatx4*)(ap + kf * 32 + 4);
        }
    }

    for (int t = tbase; t < M_TILES; t += 1250) {
        int m0 = t * 16;

        // hoist norm loads so they overlap the MFMA chain
        float s1r[4], s2r[4];
#pragma unroll
        for (int r = 0; r < 4; r++) {
            int node = m0 + quad * 4 + r;
            s1r[r] = norm1[node];
            s2r[r] = norm2[node];
        }

        // convert current tile (consumes pf -> frees it for next prefetch)
        half8 a[8];
#pragma unroll
        for (int kf = 0; kf < 8; kf++) {
            floatx4 f0 = pf[2 * kf];
            floatx4 f1 = pf[2 * kf + 1];
            half8 h;
            h[0] = (f16)f0.x; h[1] = (f16)f0.y; h[2] = (f16)f0.z; h[3] = (f16)f0.w;
            h[4] = (f16)f1.x; h[5] = (f16)f1.y; h[6] = (f16)f1.z; h[7] = (f16)f1.w;
            a[kf] = h;
        }

        // issue next tile's prefetch: in flight under the MFMAs + epilogue
        int tn = t + 1250;
        if (tn >= M_TILES) tn = tbase; // dummy (in-bounds) prefetch on last iter
        {
            const float* apn = feat + (size_t)tn * 16 * 256 + arow;
#pragma unroll
            for (int kf = 0; kf < 8; kf++) {
                pf[2 * kf] = *(const floatx4*)(apn + kf * 32);
                pf[2 * kf + 1] = *(const floatx4*)(apn + kf * 32 + 4);
            }
        }

        floatx4 acc0 = (floatx4){0.f, 0.f, 0.f, 0.f};
        floatx4 acc1 = (floatx4){0.f, 0.f, 0.f, 0.f};
#pragma unroll
        for (int kf = 0; kf < 8; kf++) {
            acc0 = __builtin_amdgcn_mfma_f32_16x16x32_f16(a[kf], b[0][kf], acc0, 0, 0, 0);
            acc1 = __builtin_amdgcn_mfma_f32_16x16x32_f16(a[kf], b[1][kf], acc1, 0, 0, 0);
        }

        // epilogue: paired (m,v) 4 B stores
#pragma unroll
        for (int r = 0; r < 4; r++) {
            int node = m0 + quad * 4 + r;
            float m = fmaxf(acc0[r], 0.f);
            float v = fmaxf(acc1[r], 0.f);
            float att = __expf(-v); // GAMMA = 1
            half2v pr;
            pr[0] = (f16)(m * att * s1r[r]);
            pr[1] = (f16)(v * att * att * s2r[r]);
            *(half2v*)(msg + (size_t)node * 256 + col * 2) = pr;
        }
    }
}

// ---------------- per-dst aggregation (wave per dst) + final norm ----------------
// msg row: 128 interleaved (m,v) f16 pairs (512 B). lane covers cols 2*lane, 2*lane+1
// via ONE 8 B load per edge: half4 = {m[2l], v[2l], m[2l+1], v[2l+1]}.
__global__ __launch_bounds__(256) void agg_kernel(const int* __restrict__ row_start,
                                                  const int* __restrict__ srcs,
                                                  const f16* __restrict__ msg,
                                                  const float* __restrict__ norm1,
                                                  const float* __restrict__ norm2,
                                                  float* __restrict__ out_mean,
                                                  float* __restrict__ out_var) {
    int d = blockIdx.x * 4 + (threadIdx.x >> 6);
    int lane = threadIdx.x & 63;
    int s0 = row_start[d];
    int s1 = row_start[d + 1];
    float am0 = 0.f, am1 = 0.f, av0 = 0.f, av1 = 0.f;
    int i = s0;
    for (; i + 7 < s1; i += 8) {
        half4 h[8];
#pragma unroll
        for (int j = 0; j < 8; j++) {
            h[j] = *(const half4*)(msg + (size_t)srcs[i + j] * 256 + lane * 4);
        }
#pragma unroll
        for (int j = 0; j < 8; j++) {
            am0 += (float)h[j][0];
            av0 += (float)h[j][1];
            am1 += (float)h[j][2];
            av1 += (float)h[j][3];
        }
    }
    for (; i < s1; i++) {
        half4 ha = *(const half4*)(msg + (size_t)srcs[i] * 256 + lane * 4);
        am0 += (float)ha[0];
        av0 += (float)ha[1];
        am1 += (float)ha[2];
        av1 += (float)ha[3];
    }
    float k1 = norm1[d], k2 = norm2[d];
    float2 om = make_float2(am0 * k1, am1 * k1);
    float2 ov = make_float2(av0 * k2, av1 * k2);
    *(float2*)(out_mean + (size_t)d * 128 + lane * 2) = om;
    *(float2*)(out_var + (size_t)d * 128 + lane * 2) = ov;
}

extern "C" void kernel_launch(void* const* d_in, const int* in_sizes, int n_in,
                              void* d_out, int out_size, void* d_ws, size_t ws_size,
                              hipStream_t stream) {
    const float* feat = (const float*)d_in[0];
    const float* Wm = (const float*)d_in[1];
    const float* Wv = (const float*)d_in[2];
    const int* src = (const int*)d_in[3];
    const int* dst = (const int*)d_in[4];
    float* out = (float*)d_out;

    const int N = N_NODES;
    const int E = N_EDGES;

    char* wsp = (char*)d_ws;
    auto carve = [&](size_t bytes) {
        char* p = wsp;
        wsp += (bytes + 255) & ~(size_t)255;
        return p;
    };
    f16* msg = (f16*)carve((size_t)N * 256 * sizeof(f16));   // (m,v) pairs, 51.2 MB
    f16* Bt = (f16*)carve((size_t)256 * 256 * sizeof(f16));  // 128 KB
    int* srcs_sorted = (int*)carve((size_t)E * 4);
    int* rank = (int*)carve((size_t)E * 4);
    int* deg = (int*)carve((size_t)N * 4);
    int* row_start = (int*)carve((size_t)(N + 1) * 4);
    float* norm1 = (float*)carve((size_t)N * 4);
    float* norm2 = (float*)carve((size_t)N * 4);
    int* partial = (int*)carve(128 * 4);

    hipMemsetAsync(deg, 0, (size_t)N * 4, stream);

    count_rank_kernel<<<(E + 255) / 256, 256, 0, stream>>>(dst, E, deg, rank);
    convert_B_kernel<<<256, 256, 0, stream>>>(Wm, Wv, Bt);
    scan_partial_kernel<<<SCAN_BLOCKS, 256, 0, stream>>>(deg, N, partial);
    scan_top_kernel<<<1, 128, 0, stream>>>(partial, SCAN_BLOCKS, row_start, N);
    scan_final_kernel<<<SCAN_BLOCKS, 256, 0, stream>>>(deg, N, partial, row_start, norm1, norm2);
    scatter_edges_kernel<<<(E + 255) / 256, 256, 0, stream>>>(src, dst, rank, row_start, E,
                                                              srcs_sorted);
    proj_mfma_kernel<<<2500, 256, 0, stream>>>(feat, Bt, norm1, norm2, msg);
    agg_kernel<<<N / 4, 256, 0, stream>>>(row_start, srcs_sorted, msg, norm1, norm2,
                                          out, out + (size_t)N * OUTF);
}

// Round 3
// 434.947 us; speedup vs baseline: 1.1660x; 1.1660x over previous
//
#include <hip/hip_runtime.h>
#include <hip/hip_bf16.h>

#define N_NODES 100000
#define N_EDGES 1600000
#define OUTF 128
#define INF 256
#define SCAN_CHUNK 1024
#define SCAN_BLOCKS 98   // 98*1024 = 100352 >= 100000
#define M_TILES 6250     // 100000 / 16

typedef _Float16 f16;
typedef _Float16 half8 __attribute__((ext_vector_type(8)));
typedef _Float16 half4 __attribute__((ext_vector_type(4)));
typedef _Float16 half2v __attribute__((ext_vector_type(2)));
typedef float floatx4 __attribute__((ext_vector_type(4)));

// ---------------- fused degree count + edge rank (ONE atomic pass) ----------------
__global__ void count_rank_kernel(const int* __restrict__ dst, int E,
                                  int* __restrict__ deg, int* __restrict__ rank) {
    int i = blockIdx.x * blockDim.x + threadIdx.x;
    if (i < E) rank[i] = atomicAdd(&deg[dst[i]], 1);
}

// ---------------- scan step 1: per-chunk sums ----------------
__global__ __launch_bounds__(256) void scan_partial_kernel(const int* __restrict__ deg, int n,
                                                           int* __restrict__ partial) {
    __shared__ int red[256];
    int b = blockIdx.x, t = threadIdx.x;
    int base = b * SCAN_CHUNK;
    int s = 0;
    for (int i = t; i < SCAN_CHUNK; i += 256) {
        int idx = base + i;
        if (idx < n) s += deg[idx];
    }
    red[t] = s;
    __syncthreads();
    for (int off = 128; off > 0; off >>= 1) {
        if (t < off) red[t] += red[t + off];
        __syncthreads();
    }
    if (t == 0) partial[b] = red[0];
}

// ---------------- scan step 2: exclusive scan of partials (nb <= 128) ----------------
__global__ __launch_bounds__(128) void scan_top_kernel(int* __restrict__ partial, int nb,
                                                       int* __restrict__ row_start, int n) {
    __shared__ int sc[128];
    int t = threadIdx.x;
    int v = (t < nb) ? partial[t] : 0;
    sc[t] = v;
    __syncthreads();
    for (int off = 1; off < 128; off <<= 1) {
        int val = sc[t];
        int add = (t >= off) ? sc[t - off] : 0;
        __syncthreads();
        sc[t] = val + add;
        __syncthreads();
    }
    if (t < nb) partial[t] = sc[t] - v;   // exclusive
    if (t == 127) row_start[n] = sc[127]; // total edge count
}

// ---------------- scan step 3: per-chunk exclusive scan + norms ----------------
__global__ __launch_bounds__(256) void scan_final_kernel(const int* __restrict__ deg, int n,
                                                         const int* __restrict__ partial,
                                                         int* __restrict__ row_start,
                                                         float* __restrict__ norm1,
                                                         float* __restrict__ norm2) {
    __shared__ int sc[256];
    int b = blockIdx.x, t = threadIdx.x;
    int base = b * SCAN_CHUNK + t * 4;
    int v[4];
    int tsum = 0;
#pragma unroll
    for (int j = 0; j < 4; j++) {
        int idx = base + j;
        v[j] = (idx < n) ? deg[idx] : 0;
        tsum += v[j];
    }
    sc[t] = tsum;
    __syncthreads();
    for (int off = 1; off < 256; off <<= 1) {
        int val = sc[t];
        int add = (t >= off) ? sc[t - off] : 0;
        __syncthreads();
        sc[t] = val + add;
        __syncthreads();
    }
    int run = sc[t] - tsum + partial[b];
#pragma unroll
    for (int j = 0; j < 4; j++) {
        int idx = base + j;
        if (idx < n) {
            row_start[idx] = run;
            float d = (float)(v[j] > 0 ? v[j] : 1); // clip(deg, 1)
            norm1[idx] = rsqrtf(d);
            norm2[idx] = 1.0f / d;
            run += v[j];
        }
    }
}

// ---------------- edge scatter into CSR slots (atomic-free) ----------------
__global__ void scatter_edges_kernel(const int* __restrict__ src, const int* __restrict__ dst,
                                     const int* __restrict__ rank,
                                     const int* __restrict__ row_start,
                                     int E, int* __restrict__ srcs_sorted) {
    int i = blockIdx.x * blockDim.x + threadIdx.x;
    if (i < E) {
        srcs_sorted[row_start[dst[i]] + rank[i]] = src[i];
    }
}

// ---------------- convert W_mean|W_var into f16 Bt, wave-friendly layout ----------------
// Bt row ng = g*16 + i, g in [0,16): g = ch*8 + w*2 + cg
//   ch = column half (0/1), w = wave (0..3), cg: 0 -> mean, 1 -> var
// actual col = ch*64 + w*16 + i (0..127);  Bt[ng][k] = W[k][col]
__global__ __launch_bounds__(256) void convert_B_kernel(const float* __restrict__ Wm,
                                                        const float* __restrict__ Wv,
                                                        f16* __restrict__ Bt) {
    int k = threadIdx.x;
    int ng = blockIdx.x;
    int g = ng >> 4, i = ng & 15;
    int ch = g >> 3, w = (g >> 1) & 3, cg = g & 1;
    int col = ch * 64 + w * 16 + i;
    const float* srcW = cg ? Wv : Wm;
    Bt[ng * 256 + k] = (f16)srcW[k * 128 + col];
}

// ---------------- MFMA projection + relu + attention + msg (f16) ----------------
// block = 256 (4 waves). Grid = 2500: blockIdx&1 = column half, blockIdx>>1 = tile
// chunk (1250 chunks x 5 tiles grid-stride). Wave w owns 16 cols for mean & var.
//
// R2 post-mortem: VGPR=84 -> B pin worked, but pf[16] (64 VGPR) was demoted to
// point-of-use loads; the A-load chain stayed latency-serialized (122-139 us,
// all pipes <8%). Lesson: can't out-argue the register allocator.
// R3: LDS double-buffered staging via global_load_lds width=16 (m97 structure):
//  - A tile (16 KB) staged ONCE per block (was 4x redundant per-wave loads)
//  - stage(t+1) issued before compute(t); compiler's vmcnt(0) lands at the NEXT
//    barrier -> loads in flight under MFMA+cvt+epilogue. Compiler preserves this.
//  - 16B-granule XOR swizzle (byte ^= (row&7)<<4) applied on the GLOBAL source
//    (LDS dest stays linear, rule #21) and on the ds_read address: without it
//    each quad's 16 lanes read stride-1024 = same bank.
// B fragments stay register-pinned (proven at R2).
__global__ __launch_bounds__(256, 3) void proj_mfma_kernel(const float* __restrict__ feat,
                                                           const f16* __restrict__ Bt,
                                                           const float* __restrict__ norm1,
                                                           const float* __restrict__ norm2,
                                                           f16* __restrict__ msg) {
    __shared__ float As[2][16 * 256]; // 2 x 16 KB double buffer

    int tid = threadIdx.x;
    int w = tid >> 6;
    int lane = tid & 63;
    int quad = lane >> 4;
    int l15 = lane & 15;
    int ch = blockIdx.x & 1;
    int tbase = blockIdx.x >> 1;

    // load B fragments once: 2 col-groups (mean/var, same 16 cols) x 8 k-frags
    half8 b[2][8];
#pragma unroll
    for (int cg = 0; cg < 2; cg++) {
        int g = ch * 8 + w * 2 + cg;
        const f16* bp = Bt + (size_t)(g * 16 + l15) * 256 + quad * 8;
#pragma unroll
        for (int kf = 0; kf < 8; kf++) {
            b[cg][kf] = *(const half8*)(bp + kf * 32);
        }
    }
    // pin: forces register residency across the loop (allocator can't sink/remat)
#pragma unroll
    for (int cg = 0; cg < 2; cg++) {
#pragma unroll
        for (int kf = 0; kf < 8; kf++) {
            asm volatile("" : "+v"(b[cg][kf]));
        }
    }

    int col = ch * 64 + w * 16 + l15; // 0..127

    // swizzled ds_read byte addresses for this lane (row = l15):
    // global in-row chunk X = quad*32 (+16); LDS slot = X ^ ((row&7)<<4).
    // kf*128 has no bits in the XOR range (4..6) so it adds cleanly.
    int swz = (l15 & 7) << 4;
    int rb0 = l15 * 1024 + ((quad * 32) ^ swz);
    int rb1 = l15 * 1024 + ((quad * 32 + 16) ^ swz);

    // per-lane swizzled global source offset within a row, for staging row r:
    // LDS[r*1024 + lane*16] <- rowbytes[(lane*16) ^ ((r&7)<<4)]
    int lsw = lane * 16;

    // wave w stages rows w*4 .. w*4+3 of each tile (1 KB per instruction)
    auto stage = [&](int buf, int t) {
        int m0 = t * 16;
#pragma unroll
        for (int j = 0; j < 4; j++) {
            int r = w * 4 + j;
            const char* gp = (const char*)(feat + (size_t)(m0 + r) * 256)
                             + (lsw ^ ((r & 7) << 4));
            char* lp = (char*)&As[buf][0] + r * 1024; // wave-uniform base
            __builtin_amdgcn_global_load_lds(
                (const __attribute__((address_space(1))) void*)gp,
                (__attribute__((address_space(3))) void*)lp, 16, 0, 0);
        }
    };

    // prologue: stage first tile into buf 0
    stage(0, tbase);
    int cur = 0;

    for (int t = tbase; t < M_TILES; t += 1250) {
        __syncthreads(); // drains staging of buf[cur]; all prior reads of buf[cur^1] done

        int tn = t + 1250;
        if (tn < M_TILES) stage(cur ^ 1, tn); // in flight under this tile's compute

        // ds_read + cvt from buf[cur]
        const char* ab = (const char*)&As[cur][0];
        half8 a[8];
#pragma unroll
        for (int kf = 0; kf < 8; kf++) {
            floatx4 f0 = *(const floatx4*)(ab + rb0 + kf * 128);
            floatx4 f1 = *(const floatx4*)(ab + rb1 + kf * 128);
            half8 h;
            h[0] = (f16)f0.x; h[1] = (f16)f0.y; h[2] = (f16)f0.z; h[3] = (f16)f0.w;
            h[4] = (f16)f1.x; h[5] = (f16)f1.y; h[6] = (f16)f1.z; h[7] = (f16)f1.w;
            a[kf] = h;
        }

        int m0 = t * 16;
        // hoist norm loads so they overlap the MFMA chain
        float s1r[4], s2r[4];
#pragma unroll
        for (int r = 0; r < 4; r++) {
            int node = m0 + quad * 4 + r;
            s1r[r] = norm1[node];
            s2r[r] = norm2[node];
        }

        floatx4 acc0 = (floatx4){0.f, 0.f, 0.f, 0.f};
        floatx4 acc1 = (floatx4){0.f, 0.f, 0.f, 0.f};
#pragma unroll
        for (int kf = 0; kf < 8; kf++) {
            acc0 = __builtin_amdgcn_mfma_f32_16x16x32_f16(a[kf], b[0][kf], acc0, 0, 0, 0);
            acc1 = __builtin_amdgcn_mfma_f32_16x16x32_f16(a[kf], b[1][kf], acc1, 0, 0, 0);
        }

        // epilogue: paired (m,v) 4 B stores
#pragma unroll
        for (int r = 0; r < 4; r++) {
            int node = m0 + quad * 4 + r;
            float m = fmaxf(acc0[r], 0.f);
            float v = fmaxf(acc1[r], 0.f);
            float att = __expf(-v); // GAMMA = 1
            half2v pr;
            pr[0] = (f16)(m * att * s1r[r]);
            pr[1] = (f16)(v * att * att * s2r[r]);
            *(half2v*)(msg + (size_t)node * 256 + col * 2) = pr;
        }
        cur ^= 1;
    }
}

// ---------------- per-dst aggregation (wave per dst) + final norm ----------------
// msg row: 128 interleaved (m,v) f16 pairs (512 B). lane covers cols 2*lane, 2*lane+1
// via ONE 8 B load per edge: half4 = {m[2l], v[2l], m[2l+1], v[2l+1]}.
__global__ __launch_bounds__(256) void agg_kernel(const int* __restrict__ row_start,
                                                  const int* __restrict__ srcs,
                                                  const f16* __restrict__ msg,
                                                  const float* __restrict__ norm1,
                                                  const float* __restrict__ norm2,
                                                  float* __restrict__ out_mean,
                                                  float* __restrict__ out_var) {
    int d = blockIdx.x * 4 + (threadIdx.x >> 6);
    int lane = threadIdx.x & 63;
    int s0 = row_start[d];
    int s1 = row_start[d + 1];
    float am0 = 0.f, am1 = 0.f, av0 = 0.f, av1 = 0.f;
    int i = s0;
    for (; i + 7 < s1; i += 8) {
        half4 h[8];
#pragma unroll
        for (int j = 0; j < 8; j++) {
            h[j] = *(const half4*)(msg + (size_t)srcs[i + j] * 256 + lane * 4);
        }
#pragma unroll
        for (int j = 0; j < 8; j++) {
            am0 += (float)h[j][0];
            av0 += (float)h[j][1];
            am1 += (float)h[j][2];
            av1 += (float)h[j][3];
        }
    }
    for (; i < s1; i++) {
        half4 ha = *(const half4*)(msg + (size_t)srcs[i] * 256 + lane * 4);
        am0 += (float)ha[0];
        av0 += (float)ha[1];
        am1 += (float)ha[2];
        av1 += (float)ha[3];
    }
    float k1 = norm1[d], k2 = norm2[d];
    float2 om = make_float2(am0 * k1, am1 * k1);
    float2 ov = make_float2(av0 * k2, av1 * k2);
    *(float2*)(out_mean + (size_t)d * 128 + lane * 2) = om;
    *(float2*)(out_var + (size_t)d * 128 + lane * 2) = ov;
}

extern "C" void kernel_launch(void* const* d_in, const int* in_sizes, int n_in,
                              void* d_out, int out_size, void* d_ws, size_t ws_size,
                              hipStream_t stream) {
    const float* feat = (const float*)d_in[0];
    const float* Wm = (const float*)d_in[1];
    const float* Wv = (const float*)d_in[2];
    const int* src = (const int*)d_in[3];
    const int* dst = (const int*)d_in[4];
    float* out = (float*)d_out;

    const int N = N_NODES;
    const int E = N_EDGES;

    char* wsp = (char*)d_ws;
    auto carve = [&](size_t bytes) {
        char* p = wsp;
        wsp += (bytes + 255) & ~(size_t)255;
        return p;
    };
    f16* msg = (f16*)carve((size_t)N * 256 * sizeof(f16));   // (m,v) pairs, 51.2 MB
    f16* Bt = (f16*)carve((size_t)256 * 256 * sizeof(f16));  // 128 KB
    int* srcs_sorted = (int*)carve((size_t)E * 4);
    int* rank = (int*)carve((size_t)E * 4);
    int* deg = (int*)carve((size_t)N * 4);
    int* row_start = (int*)carve((size_t)(N + 1) * 4);
    float* norm1 = (float*)carve((size_t)N * 4);
    float* norm2 = (float*)carve((size_t)N * 4);
    int* partial = (int*)carve(128 * 4);

    hipMemsetAsync(deg, 0, (size_t)N * 4, stream);

    count_rank_kernel<<<(E + 255) / 256, 256, 0, stream>>>(dst, E, deg, rank);
    convert_B_kernel<<<256, 256, 0, stream>>>(Wm, Wv, Bt);
    scan_partial_kernel<<<SCAN_BLOCKS, 256, 0, stream>>>(deg, N, partial);
    scan_top_kernel<<<1, 128, 0, stream>>>(partial, SCAN_BLOCKS, row_start, N);
    scan_final_kernel<<<SCAN_BLOCKS, 256, 0, stream>>>(deg, N, partial, row_start, norm1, norm2);
    scatter_edges_kernel<<<(E + 255) / 256, 256, 0, stream>>>(src, dst, rank, row_start, E,
                                                              srcs_sorted);
    proj_mfma_kernel<<<2500, 256, 0, stream>>>(feat, Bt, norm1, norm2, msg);
    agg_kernel<<<N / 4, 256, 0, stream>>>(row_start, srcs_sorted, msg, norm1, norm2,
                                          out, out + (size_t)N * OUTF);
}

// Round 4
// 430.050 us; speedup vs baseline: 1.1793x; 1.0114x over previous
//
#include <hip/hip_runtime.h>
#include <hip/hip_bf16.h>

#define N_NODES 100000
#define N_EDGES 1600000
#define OUTF 128
#define INF 256
#define SCAN_CHUNK 1024
#define SCAN_BLOCKS 98   // 98*1024 = 100352 >= 100000
#define M_TILES 6250     // 100000 / 16

typedef _Float16 f16;
typedef _Float16 half8 __attribute__((ext_vector_type(8)));
typedef _Float16 half4 __attribute__((ext_vector_type(4)));
typedef _Float16 half2v __attribute__((ext_vector_type(2)));
typedef float floatx4 __attribute__((ext_vector_type(4)));

// ---------------- fused degree count + edge rank (ONE atomic pass) ----------------
__global__ void count_rank_kernel(const int* __restrict__ dst, int E,
                                  int* __restrict__ deg, int* __restrict__ rank) {
    int i = blockIdx.x * blockDim.x + threadIdx.x;
    if (i < E) rank[i] = atomicAdd(&deg[dst[i]], 1);
}

// ---------------- scan step 1: per-chunk sums ----------------
__global__ __launch_bounds__(256) void scan_partial_kernel(const int* __restrict__ deg, int n,
                                                           int* __restrict__ partial) {
    __shared__ int red[256];
    int b = blockIdx.x, t = threadIdx.x;
    int base = b * SCAN_CHUNK;
    int s = 0;
    for (int i = t; i < SCAN_CHUNK; i += 256) {
        int idx = base + i;
        if (idx < n) s += deg[idx];
    }
    red[t] = s;
    __syncthreads();
    for (int off = 128; off > 0; off >>= 1) {
        if (t < off) red[t] += red[t + off];
        __syncthreads();
    }
    if (t == 0) partial[b] = red[0];
}

// ---------------- scan step 2: exclusive scan of partials (nb <= 128) ----------------
__global__ __launch_bounds__(128) void scan_top_kernel(int* __restrict__ partial, int nb,
                                                       int* __restrict__ row_start, int n) {
    __shared__ int sc[128];
    int t = threadIdx.x;
    int v = (t < nb) ? partial[t] : 0;
    sc[t] = v;
    __syncthreads();
    for (int off = 1; off < 128; off <<= 1) {
        int val = sc[t];
        int add = (t >= off) ? sc[t - off] : 0;
        __syncthreads();
        sc[t] = val + add;
        __syncthreads();
    }
    if (t < nb) partial[t] = sc[t] - v;   // exclusive
    if (t == 127) row_start[n] = sc[127]; // total edge count
}

// ---------------- scan step 3: per-chunk exclusive scan + norms ----------------
__global__ __launch_bounds__(256) void scan_final_kernel(const int* __restrict__ deg, int n,
                                                         const int* __restrict__ partial,
                                                         int* __restrict__ row_start,
                                                         float* __restrict__ norm1,
                                                         float* __restrict__ norm2) {
    __shared__ int sc[256];
    int b = blockIdx.x, t = threadIdx.x;
    int base = b * SCAN_CHUNK + t * 4;
    int v[4];
    int tsum = 0;
#pragma unroll
    for (int j = 0; j < 4; j++) {
        int idx = base + j;
        v[j] = (idx < n) ? deg[idx] : 0;
        tsum += v[j];
    }
    sc[t] = tsum;
    __syncthreads();
    for (int off = 1; off < 256; off <<= 1) {
        int val = sc[t];
        int add = (t >= off) ? sc[t - off] : 0;
        __syncthreads();
        sc[t] = val + add;
        __syncthreads();
    }
    int run = sc[t] - tsum + partial[b];
#pragma unroll
    for (int j = 0; j < 4; j++) {
        int idx = base + j;
        if (idx < n) {
            row_start[idx] = run;
            float d = (float)(v[j] > 0 ? v[j] : 1); // clip(deg, 1)
            norm1[idx] = rsqrtf(d);
            norm2[idx] = 1.0f / d;
            run += v[j];
        }
    }
}

// ---------------- edge scatter into CSR slots (atomic-free) ----------------
__global__ void scatter_edges_kernel(const int* __restrict__ src, const int* __restrict__ dst,
                                     const int* __restrict__ rank,
                                     const int* __restrict__ row_start,
                                     int E, int* __restrict__ srcs_sorted) {
    int i = blockIdx.x * blockDim.x + threadIdx.x;
    if (i < E) {
        srcs_sorted[row_start[dst[i]] + rank[i]] = src[i];
    }
}

// ---------------- convert W_mean|W_var into f16 Bt, wave-friendly layout ----------------
// Bt row ng = g*16 + i, g in [0,16): g = ch*8 + w*2 + cg
//   ch = column half (0/1), w = wave (0..3), cg: 0 -> mean, 1 -> var
// actual col = ch*64 + w*16 + i (0..127);  Bt[ng][k] = W[k][col]
__global__ __launch_bounds__(256) void convert_B_kernel(const float* __restrict__ Wm,
                                                        const float* __restrict__ Wv,
                                                        f16* __restrict__ Bt) {
    int k = threadIdx.x;
    int ng = blockIdx.x;
    int g = ng >> 4, i = ng & 15;
    int ch = g >> 3, w = (g >> 1) & 3, cg = g & 1;
    int col = ch * 64 + w * 16 + i;
    const float* srcW = cg ? Wv : Wm;
    Bt[ng * 256 + k] = (f16)srcW[k * 128 + col];
}

// ---------------- MFMA projection + relu + attention + msg (f16) ----------------
// block = 256 (4 waves), LDS double-buffered A staging via global_load_lds (R3: this
// removed proj from the top-5; ~67 us inferred).
// R4: XCD ch-pair swizzle. The two ch-halves of the same M-chunk read the SAME
// 16 KB feat tile; default round-robin put them on different XCDs (FETCH showed
// 2x feat = 102 MB). Map them to hw blocks b and b+8 (same b%8 -> same XCD) so
// the second read hits that XCD's L2. Predicted proj FETCH 102 -> ~55 MB.
__global__ __launch_bounds__(256, 3) void proj_mfma_kernel(const float* __restrict__ feat,
                                                           const f16* __restrict__ Bt,
                                                           const float* __restrict__ norm1,
                                                           const float* __restrict__ norm2,
                                                           f16* __restrict__ msg) {
    __shared__ float As[2][16 * 256]; // 2 x 16 KB double buffer

    int tid = threadIdx.x;
    int w = tid >> 6;
    int lane = tid & 63;
    int quad = lane >> 4;
    int l15 = lane & 15;

    // ch-pair -> same-XCD mapping: hw blocks b and b+8 handle ch 0/1 of pair jj
    int bidx = blockIdx.x;
    int jj, ch;
    if (bidx < 2496) {
        jj = (bidx >> 4) * 8 + (bidx & 7);
        ch = (bidx >> 3) & 1;
    } else {
        int r = bidx - 2496;
        jj = 1248 + (r >> 1);
        ch = r & 1;
    }
    int tbase = jj;

    // load B fragments once: 2 col-groups (mean/var, same 16 cols) x 8 k-frags
    half8 b[2][8];
#pragma unroll
    for (int cg = 0; cg < 2; cg++) {
        int g = ch * 8 + w * 2 + cg;
        const f16* bp = Bt + (size_t)(g * 16 + l15) * 256 + quad * 8;
#pragma unroll
        for (int kf = 0; kf < 8; kf++) {
            b[cg][kf] = *(const half8*)(bp + kf * 32);
        }
    }
    // pin: forces register residency across the loop (allocator can't sink/remat)
#pragma unroll
    for (int cg = 0; cg < 2; cg++) {
#pragma unroll
        for (int kf = 0; kf < 8; kf++) {
            asm volatile("" : "+v"(b[cg][kf]));
        }
    }

    int col = ch * 64 + w * 16 + l15; // 0..127

    // swizzled ds_read byte addresses for this lane (row = l15):
    // global in-row chunk X = quad*32 (+16); LDS slot = X ^ ((row&7)<<4).
    // kf*128 has no bits in the XOR range (4..6) so it adds cleanly.
    int swz = (l15 & 7) << 4;
    int rb0 = l15 * 1024 + ((quad * 32) ^ swz);
    int rb1 = l15 * 1024 + ((quad * 32 + 16) ^ swz);

    // per-lane swizzled global source offset within a row, for staging row r:
    // LDS[r*1024 + lane*16] <- rowbytes[(lane*16) ^ ((r&7)<<4)]
    int lsw = lane * 16;

    // wave w stages rows w*4 .. w*4+3 of each tile (1 KB per instruction)
    auto stage = [&](int buf, int t) {
        int m0 = t * 16;
#pragma unroll
        for (int j = 0; j < 4; j++) {
            int r = w * 4 + j;
            const char* gp = (const char*)(feat + (size_t)(m0 + r) * 256)
                             + (lsw ^ ((r & 7) << 4));
            char* lp = (char*)&As[buf][0] + r * 1024; // wave-uniform base
            __builtin_amdgcn_global_load_lds(
                (const __attribute__((address_space(1))) void*)gp,
                (__attribute__((address_space(3))) void*)lp, 16, 0, 0);
        }
    };

    // prologue: stage first tile into buf 0
    stage(0, tbase);
    int cur = 0;

    for (int t = tbase; t < M_TILES; t += 1250) {
        __syncthreads(); // drains staging of buf[cur]; all prior reads of buf[cur^1] done

        int tn = t + 1250;
        if (tn < M_TILES) stage(cur ^ 1, tn); // in flight under this tile's compute

        // ds_read + cvt from buf[cur]
        const char* ab = (const char*)&As[cur][0];
        half8 a[8];
#pragma unroll
        for (int kf = 0; kf < 8; kf++) {
            floatx4 f0 = *(const floatx4*)(ab + rb0 + kf * 128);
            floatx4 f1 = *(const floatx4*)(ab + rb1 + kf * 128);
            half8 h;
            h[0] = (f16)f0.x; h[1] = (f16)f0.y; h[2] = (f16)f0.z; h[3] = (f16)f0.w;
            h[4] = (f16)f1.x; h[5] = (f16)f1.y; h[6] = (f16)f1.z; h[7] = (f16)f1.w;
            a[kf] = h;
        }

        int m0 = t * 16;
        // hoist norm loads so they overlap the MFMA chain
        float s1r[4], s2r[4];
#pragma unroll
        for (int r = 0; r < 4; r++) {
            int node = m0 + quad * 4 + r;
            s1r[r] = norm1[node];
            s2r[r] = norm2[node];
        }

        floatx4 acc0 = (floatx4){0.f, 0.f, 0.f, 0.f};
        floatx4 acc1 = (floatx4){0.f, 0.f, 0.f, 0.f};
#pragma unroll
        for (int kf = 0; kf < 8; kf++) {
            acc0 = __builtin_amdgcn_mfma_f32_16x16x32_f16(a[kf], b[0][kf], acc0, 0, 0, 0);
            acc1 = __builtin_amdgcn_mfma_f32_16x16x32_f16(a[kf], b[1][kf], acc1, 0, 0, 0);
        }

        // epilogue: paired (m,v) 4 B stores
#pragma unroll
        for (int r = 0; r < 4; r++) {
            int node = m0 + quad * 4 + r;
            float m = fmaxf(acc0[r], 0.f);
            float v = fmaxf(acc1[r], 0.f);
            float att = __expf(-v); // GAMMA = 1
            half2v pr;
            pr[0] = (f16)(m * att * s1r[r]);
            pr[1] = (f16)(v * att * att * s2r[r]);
            *(half2v*)(msg + (size_t)node * 256 + col * 2) = pr;
        }
        cur ^= 1;
    }
}

// ---------------- per-dst aggregation (wave per dst) + final norm ----------------
// R4: 2 edges per wave. Half-wave 0 (lanes 0-31) takes even-parity edges, half-wave
// 1 odd-parity. Lane j = lane&31 loads ONE half8 (16 B = cols 4j..4j+3 as (m,v)
// pairs) per edge -> 4x fewer gather instructions than R3's per-edge 8 B loads,
// 2x bytes in flight per instruction. No parity tail (each half covers its class).
// Per-dst finish: 8x shfl_xor(32) combine, lanes 0-31 write float4 per array.
// Output stores are NONTEMPORAL: the 100 MB streaming out-write must not evict
// the 51.2 MB msg gather working set from L3.
__global__ __launch_bounds__(256) void agg_kernel(const int* __restrict__ row_start,
                                                  const int* __restrict__ srcs,
                                                  const f16* __restrict__ msg,
                                                  const float* __restrict__ norm1,
                                                  const float* __restrict__ norm2,
                                                  float* __restrict__ out_mean,
                                                  float* __restrict__ out_var) {
    int d = blockIdx.x * 4 + (threadIdx.x >> 6);
    int lane = threadIdx.x & 63;
    int half = lane >> 5;   // 0: even edges, 1: odd edges
    int j = lane & 31;      // col group: cols 4j..4j+3

    int s0 = row_start[d];
    int s1 = row_start[d + 1];

    float am0 = 0.f, am1 = 0.f, am2 = 0.f, am3 = 0.f;
    float av0 = 0.f, av1 = 0.f, av2 = 0.f, av3 = 0.f;

    int i = s0 + half;
    // 4 edges per half-wave per iteration (8 edges total)
    for (; i + 6 < s1; i += 8) {
        int sa = srcs[i], sb = srcs[i + 2], sc = srcs[i + 4], sd = srcs[i + 6];
        half8 ha = *(const half8*)(msg + (size_t)sa * 256 + j * 8);
        half8 hb = *(const half8*)(msg + (size_t)sb * 256 + j * 8);
        half8 hc = *(const half8*)(msg + (size_t)sc * 256 + j * 8);
        half8 hd = *(const half8*)(msg + (size_t)sd * 256 + j * 8);
        am0 += (float)ha[0] + (float)hb[0] + (float)hc[0] + (float)hd[0];
        av0 += (float)ha[1] + (float)hb[1] + (float)hc[1] + (float)hd[1];
        am1 += (float)ha[2] + (float)hb[2] + (float)hc[2] + (float)hd[2];
        av1 += (float)ha[3] + (float)hb[3] + (float)hc[3] + (float)hd[3];
        am2 += (float)ha[4] + (float)hb[4] + (float)hc[4] + (float)hd[4];
        av2 += (float)ha[5] + (float)hb[5] + (float)hc[5] + (float)hd[5];
        am3 += (float)ha[6] + (float)hb[6] + (float)hc[6] + (float)hd[6];
        av3 += (float)ha[7] + (float)hb[7] + (float)hc[7] + (float)hd[7];
    }
    for (; i < s1; i += 2) {
        int sa = srcs[i];
        half8 ha = *(const half8*)(msg + (size_t)sa * 256 + j * 8);
        am0 += (float)ha[0];
        av0 += (float)ha[1];
        am1 += (float)ha[2];
        av1 += (float)ha[3];
        am2 += (float)ha[4];
        av2 += (float)ha[5];
        am3 += (float)ha[6];
        av3 += (float)ha[7];
    }

    // combine even/odd halves (lane j gets partner j+32's partial)
    am0 += __shfl_xor(am0, 32, 64);
    am1 += __shfl_xor(am1, 32, 64);
    am2 += __shfl_xor(am2, 32, 64);
    am3 += __shfl_xor(am3, 32, 64);
    av0 += __shfl_xor(av0, 32, 64);
    av1 += __shfl_xor(av1, 32, 64);
    av2 += __shfl_xor(av2, 32, 64);
    av3 += __shfl_xor(av3, 32, 64);

    if (half == 0) {
        float k1 = norm1[d], k2 = norm2[d];
        floatx4 om = {am0 * k1, am1 * k1, am2 * k1, am3 * k1};
        floatx4 ov = {av0 * k2, av1 * k2, av2 * k2, av3 * k2};
        __builtin_nontemporal_store(om, (floatx4*)(out_mean + (size_t)d * 128 + j * 4));
        __builtin_nontemporal_store(ov, (floatx4*)(out_var + (size_t)d * 128 + j * 4));
    }
}

extern "C" void kernel_launch(void* const* d_in, const int* in_sizes, int n_in,
                              void* d_out, int out_size, void* d_ws, size_t ws_size,
                              hipStream_t stream) {
    const float* feat = (const float*)d_in[0];
    const float* Wm = (const float*)d_in[1];
    const float* Wv = (const float*)d_in[2];
    const int* src = (const int*)d_in[3];
    const int* dst = (const int*)d_in[4];
    float* out = (float*)d_out;

    const int N = N_NODES;
    const int E = N_EDGES;

    char* wsp = (char*)d_ws;
    auto carve = [&](size_t bytes) {
        char* p = wsp;
        wsp += (bytes + 255) & ~(size_t)255;
        return p;
    };
    f16* msg = (f16*)carve((size_t)N * 256 * sizeof(f16));   // (m,v) pairs, 51.2 MB
    f16* Bt = (f16*)carve((size_t)256 * 256 * sizeof(f16));  // 128 KB
    int* srcs_sorted = (int*)carve((size_t)E * 4);
    int* rank = (int*)carve((size_t)E * 4);
    int* deg = (int*)carve((size_t)N * 4);
    int* row_start = (int*)carve((size_t)(N + 1) * 4);
    float* norm1 = (float*)carve((size_t)N * 4);
    float* norm2 = (float*)carve((size_t)N * 4);
    int* partial = (int*)carve(128 * 4);

    hipMemsetAsync(deg, 0, (size_t)N * 4, stream);

    count_rank_kernel<<<(E + 255) / 256, 256, 0, stream>>>(dst, E, deg, rank);
    convert_B_kernel<<<256, 256, 0, stream>>>(Wm, Wv, Bt);
    scan_partial_kernel<<<SCAN_BLOCKS, 256, 0, stream>>>(deg, N, partial);
    scan_top_kernel<<<1, 128, 0, stream>>>(partial, SCAN_BLOCKS, row_start, N);
    scan_final_kernel<<<SCAN_BLOCKS, 256, 0, stream>>>(deg, N, partial, row_start, norm1, norm2);
    scatter_edges_kernel<<<(E + 255) / 256, 256, 0, stream>>>(src, dst, rank, row_start, E,
                                                              srcs_sorted);
    proj_mfma_kernel<<<2500, 256, 0, stream>>>(feat, Bt, norm1, norm2, msg);
    agg_kernel<<<N / 4, 256, 0, stream>>>(row_start, srcs_sorted, msg, norm1, norm2,
                                          out, out + (size_t)N * OUTF);
}

// Round 5
// 412.255 us; speedup vs baseline: 1.2302x; 1.0432x over previous
//
#include <hip/hip_runtime.h>
#include <hip/hip_bf16.h>

#define N_NODES 100000
#define N_EDGES 1600000
#define OUTF 128
#define INF 256
#define SCAN_CHUNK 1024
#define SCAN_BLOCKS 98   // 98*1024 = 100352 >= 100000
#define M_TILES 6250     // 100000 / 16

#define CNT_BLOCKS 1563  // 1563*1024 >= 1.6M edges, 4 edges/thread
#define PROJ_BLOCKS 2500
#define SCAT_BLOCKS 1563

typedef _Float16 f16;
typedef _Float16 half8 __attribute__((ext_vector_type(8)));
typedef _Float16 half4 __attribute__((ext_vector_type(4)));
typedef _Float16 half2v __attribute__((ext_vector_type(2)));
typedef float floatx4 __attribute__((ext_vector_type(4)));

// ---------------- fused: degree count + edge rank (4 edges/thread) + W->Bt convert ----
// blocks [0, CNT_BLOCKS): count role. blocks [CNT_BLOCKS, CNT_BLOCKS+256): convert role.
// Bt row ng = g*16 + i, g in [0,16): g = ch*8 + w*2 + cg; col = ch*64 + w*16 + i
__global__ void count_convB_kernel(const int* __restrict__ dst, int E,
                                   int* __restrict__ deg, int* __restrict__ rank,
                                   const float* __restrict__ Wm,
                                   const float* __restrict__ Wv,
                                   f16* __restrict__ Bt) {
    int bid = blockIdx.x;
    if (bid >= CNT_BLOCKS) {
        // convert_B role
        int ng = bid - CNT_BLOCKS;
        int k = threadIdx.x;
        int g = ng >> 4, i = ng & 15;
        int ch = g >> 3, w = (g >> 1) & 3, cg = g & 1;
        int col = ch * 64 + w * 16 + i;
        const float* srcW = cg ? Wv : Wm;
        Bt[ng * 256 + k] = (f16)srcW[k * 128 + col];
        return;
    }
    int e0 = bid * 1024 + threadIdx.x * 4;
    if (e0 + 3 < E) {
        int4 d4 = *(const int4*)(dst + e0);
        int4 r4;
        r4.x = atomicAdd(&deg[d4.x], 1);
        r4.y = atomicAdd(&deg[d4.y], 1);
        r4.z = atomicAdd(&deg[d4.z], 1);
        r4.w = atomicAdd(&deg[d4.w], 1);
        *(int4*)(rank + e0) = r4;
    } else {
        for (int j = 0; j < 4; j++) {
            int e = e0 + j;
            if (e < E) rank[e] = atomicAdd(&deg[dst[e]], 1);
        }
    }
}

// ---------------- scan step 1: per-chunk sums ----------------
__global__ __launch_bounds__(256) void scan_partial_kernel(const int* __restrict__ deg, int n,
                                                           int* __restrict__ partial) {
    __shared__ int red[256];
    int b = blockIdx.x, t = threadIdx.x;
    int base = b * SCAN_CHUNK;
    int s = 0;
    for (int i = t; i < SCAN_CHUNK; i += 256) {
        int idx = base + i;
        if (idx < n) s += deg[idx];
    }
    red[t] = s;
    __syncthreads();
    for (int off = 128; off > 0; off >>= 1) {
        if (t < off) red[t] += red[t + off];
        __syncthreads();
    }
    if (t == 0) partial[b] = red[0];
}

// ---------------- scan step 2: exclusive scan of partials (nb <= 128) ----------------
__global__ __launch_bounds__(128) void scan_top_kernel(int* __restrict__ partial, int nb,
                                                       int* __restrict__ row_start, int n) {
    __shared__ int sc[128];
    int t = threadIdx.x;
    int v = (t < nb) ? partial[t] : 0;
    sc[t] = v;
    __syncthreads();
    for (int off = 1; off < 128; off <<= 1) {
        int val = sc[t];
        int add = (t >= off) ? sc[t - off] : 0;
        __syncthreads();
        sc[t] = val + add;
        __syncthreads();
    }
    if (t < nb) partial[t] = sc[t] - v;   // exclusive
    if (t == 127) row_start[n] = sc[127]; // total edge count
}

// ---------------- scan step 3: per-chunk exclusive scan + norms ----------------
__global__ __launch_bounds__(256) void scan_final_kernel(const int* __restrict__ deg, int n,
                                                         const int* __restrict__ partial,
                                                         int* __restrict__ row_start,
                                                         float* __restrict__ norm1,
                                                         float* __restrict__ norm2) {
    __shared__ int sc[256];
    int b = blockIdx.x, t = threadIdx.x;
    int base = b * SCAN_CHUNK + t * 4;
    int v[4];
    int tsum = 0;
#pragma unroll
    for (int j = 0; j < 4; j++) {
        int idx = base + j;
        v[j] = (idx < n) ? deg[idx] : 0;
        tsum += v[j];
    }
    sc[t] = tsum;
    __syncthreads();
    for (int off = 1; off < 256; off <<= 1) {
        int val = sc[t];
        int add = (t >= off) ? sc[t - off] : 0;
        __syncthreads();
        sc[t] = val + add;
        __syncthreads();
    }
    int run = sc[t] - tsum + partial[b];
#pragma unroll
    for (int j = 0; j < 4; j++) {
        int idx = base + j;
        if (idx < n) {
            row_start[idx] = run;
            float d = (float)(v[j] > 0 ? v[j] : 1); // clip(deg, 1)
            norm1[idx] = rsqrtf(d);
            norm2[idx] = 1.0f / d;
            run += v[j];
        }
    }
}

// ---------------- fused MFMA projection + CSR edge scatter ----------------
// Two roles in ONE launch (both depend only on scan outputs; independent of each
// other). Ids interleaved 8 proj : 5 scatter per 13 so both roles co-schedule
// from dispatch onward -- scatter's random-memory work hides under proj's
// MFMA/LDS compute (complementary pipes).
//
// proj role (2500 blocks): R3 structure -- LDS double-buffered A staging via
// global_load_lds w=16, XOR-swizzled (global-src pre-swizzle + swizzled ds_read),
// register-pinned B frags. ch = proj_id&1 (column half), tbase = proj_id>>1,
// 5 tiles grid-stride. msg layout: interleaved (m,v) pairs.
// scatter role (1563 blocks): 4 edges/thread, int4 loads of src/dst/rank,
// srcs_sorted[row_start[dst]+rank] = src.
__global__ __launch_bounds__(256, 3) void proj_scatter_kernel(
        const float* __restrict__ feat, const f16* __restrict__ Bt,
        const float* __restrict__ norm1, const float* __restrict__ norm2,
        f16* __restrict__ msg,
        const int* __restrict__ src, const int* __restrict__ dst,
        const int* __restrict__ rank, const int* __restrict__ row_start,
        int E, int* __restrict__ srcs_sorted) {
    __shared__ float As[2][16 * 256]; // 2 x 16 KB double buffer (proj role)

    int bid = blockIdx.x;
    int rr = bid % 13, q = bid / 13;
    int proj_id = -1, scat_id = -1;
    if (rr < 8) {
        proj_id = q * 8 + rr;
        if (proj_id >= PROJ_BLOCKS) { scat_id = 1560 + (proj_id - PROJ_BLOCKS); proj_id = -1; }
    } else {
        scat_id = q * 5 + (rr - 8);
    }

    if (scat_id >= 0) {
        // ---- scatter role ----
        int e0 = scat_id * 1024 + threadIdx.x * 4;
        if (e0 + 3 < E) {
            int4 s4 = *(const int4*)(src + e0);
            int4 d4 = *(const int4*)(dst + e0);
            int4 r4 = *(const int4*)(rank + e0);
            srcs_sorted[row_start[d4.x] + r4.x] = s4.x;
            srcs_sorted[row_start[d4.y] + r4.y] = s4.y;
            srcs_sorted[row_start[d4.z] + r4.z] = s4.z;
            srcs_sorted[row_start[d4.w] + r4.w] = s4.w;
        } else {
            for (int j = 0; j < 4; j++) {
                int e = e0 + j;
                if (e < E) srcs_sorted[row_start[dst[e]] + rank[e]] = src[e];
            }
        }
        return;
    }

    // ---- proj role ----
    int tid = threadIdx.x;
    int w = tid >> 6;
    int lane = tid & 63;
    int quad = lane >> 4;
    int l15 = lane & 15;
    int ch = proj_id & 1;
    int tbase = proj_id >> 1; // 0..1249

    // load B fragments once: 2 col-groups (mean/var, same 16 cols) x 8 k-frags
    half8 b[2][8];
#pragma unroll
    for (int cg = 0; cg < 2; cg++) {
        int g = ch * 8 + w * 2 + cg;
        const f16* bp = Bt + (size_t)(g * 16 + l15) * 256 + quad * 8;
#pragma unroll
        for (int kf = 0; kf < 8; kf++) {
            b[cg][kf] = *(const half8*)(bp + kf * 32);
        }
    }
    // pin: forces register residency across the loop (R2 evidence: VGPR=84 kept B)
#pragma unroll
    for (int cg = 0; cg < 2; cg++) {
#pragma unroll
        for (int kf = 0; kf < 8; kf++) {
            asm volatile("" : "+v"(b[cg][kf]));
        }
    }

    int col = ch * 64 + w * 16 + l15; // 0..127

    // swizzled ds_read byte addresses (row = l15): slot = X ^ ((row&7)<<4)
    int swz = (l15 & 7) << 4;
    int rb0 = l15 * 1024 + ((quad * 32) ^ swz);
    int rb1 = l15 * 1024 + ((quad * 32 + 16) ^ swz);
    int lsw = lane * 16;

    // wave w stages rows w*4 .. w*4+3 of each tile (1 KB per instruction)
    auto stage = [&](int buf, int t) {
        int m0 = t * 16;
#pragma unroll
        for (int j = 0; j < 4; j++) {
            int r = w * 4 + j;
            const char* gp = (const char*)(feat + (size_t)(m0 + r) * 256)
                             + (lsw ^ ((r & 7) << 4));
            char* lp = (char*)&As[buf][0] + r * 1024; // wave-uniform base
            __builtin_amdgcn_global_load_lds(
                (const __attribute__((address_space(1))) void*)gp,
                (__attribute__((address_space(3))) void*)lp, 16, 0, 0);
        }
    };

    stage(0, tbase);
    int cur = 0;

    for (int t = tbase; t < M_TILES; t += 1250) {
        __syncthreads(); // drains staging of buf[cur]

        int tn = t + 1250;
        if (tn < M_TILES) stage(cur ^ 1, tn); // in flight under this tile's compute

        const char* ab = (const char*)&As[cur][0];
        half8 a[8];
#pragma unroll
        for (int kf = 0; kf < 8; kf++) {
            floatx4 f0 = *(const floatx4*)(ab + rb0 + kf * 128);
            floatx4 f1 = *(const floatx4*)(ab + rb1 + kf * 128);
            half8 h;
            h[0] = (f16)f0.x; h[1] = (f16)f0.y; h[2] = (f16)f0.z; h[3] = (f16)f0.w;
            h[4] = (f16)f1.x; h[5] = (f16)f1.y; h[6] = (f16)f1.z; h[7] = (f16)f1.w;
            a[kf] = h;
        }

        int m0 = t * 16;
        float s1r[4], s2r[4];
#pragma unroll
        for (int r = 0; r < 4; r++) {
            int node = m0 + quad * 4 + r;
            s1r[r] = norm1[node];
            s2r[r] = norm2[node];
        }

        floatx4 acc0 = (floatx4){0.f, 0.f, 0.f, 0.f};
        floatx4 acc1 = (floatx4){0.f, 0.f, 0.f, 0.f};
#pragma unroll
        for (int kf = 0; kf < 8; kf++) {
            acc0 = __builtin_amdgcn_mfma_f32_16x16x32_f16(a[kf], b[0][kf], acc0, 0, 0, 0);
            acc1 = __builtin_amdgcn_mfma_f32_16x16x32_f16(a[kf], b[1][kf], acc1, 0, 0, 0);
        }

#pragma unroll
        for (int r = 0; r < 4; r++) {
            int node = m0 + quad * 4 + r;
            float m = fmaxf(acc0[r], 0.f);
            float v = fmaxf(acc1[r], 0.f);
            float att = __expf(-v); // GAMMA = 1
            half2v pr;
            pr[0] = (f16)(m * att * s1r[r]);
            pr[1] = (f16)(v * att * att * s2r[r]);
            *(half2v*)(msg + (size_t)node * 256 + col * 2) = pr;
        }
        cur ^= 1;
    }
}

// ---------------- per-dst aggregation (wave per dst) + final norm ----------------
// 2 edges per wave: half-wave 0 even edges, half-wave 1 odd. Lane j=lane&31 loads
// one half8 (16 B = cols 4j..4j+3 as (m,v) pairs) per edge. shfl_xor(32) combine,
// lanes 0-31 write float4 nontemporal (don't evict msg from L3).
// R4 verdict: traffic-bound at ~4.1 TB/s / 490 MB -- near its floor, parked.
__global__ __launch_bounds__(256) void agg_kernel(const int* __restrict__ row_start,
                                                  const int* __restrict__ srcs,
                                                  const f16* __restrict__ msg,
                                                  const float* __restrict__ norm1,
                                                  const float* __restrict__ norm2,
                                                  float* __restrict__ out_mean,
                                                  float* __restrict__ out_var) {
    int d = blockIdx.x * 4 + (threadIdx.x >> 6);
    int lane = threadIdx.x & 63;
    int half = lane >> 5;   // 0: even edges, 1: odd edges
    int j = lane & 31;      // col group: cols 4j..4j+3

    int s0 = row_start[d];
    int s1 = row_start[d + 1];

    float am0 = 0.f, am1 = 0.f, am2 = 0.f, am3 = 0.f;
    float av0 = 0.f, av1 = 0.f, av2 = 0.f, av3 = 0.f;

    int i = s0 + half;
    for (; i + 6 < s1; i += 8) {
        int sa = srcs[i], sb = srcs[i + 2], sc = srcs[i + 4], sd = srcs[i + 6];
        half8 ha = *(const half8*)(msg + (size_t)sa * 256 + j * 8);
        half8 hb = *(const half8*)(msg + (size_t)sb * 256 + j * 8);
        half8 hc = *(const half8*)(msg + (size_t)sc * 256 + j * 8);
        half8 hd = *(const half8*)(msg + (size_t)sd * 256 + j * 8);
        am0 += (float)ha[0] + (float)hb[0] + (float)hc[0] + (float)hd[0];
        av0 += (float)ha[1] + (float)hb[1] + (float)hc[1] + (float)hd[1];
        am1 += (float)ha[2] + (float)hb[2] + (float)hc[2] + (float)hd[2];
        av1 += (float)ha[3] + (float)hb[3] + (float)hc[3] + (float)hd[3];
        am2 += (float)ha[4] + (float)hb[4] + (float)hc[4] + (float)hd[4];
        av2 += (float)ha[5] + (float)hb[5] + (float)hc[5] + (float)hd[5];
        am3 += (float)ha[6] + (float)hb[6] + (float)hc[6] + (float)hd[6];
        av3 += (float)ha[7] + (float)hb[7] + (float)hc[7] + (float)hd[7];
    }
    for (; i < s1; i += 2) {
        int sa = srcs[i];
        half8 ha = *(const half8*)(msg + (size_t)sa * 256 + j * 8);
        am0 += (float)ha[0];
        av0 += (float)ha[1];
        am1 += (float)ha[2];
        av1 += (float)ha[3];
        am2 += (float)ha[4];
        av2 += (float)ha[5];
        am3 += (float)ha[6];
        av3 += (float)ha[7];
    }

    am0 += __shfl_xor(am0, 32, 64);
    am1 += __shfl_xor(am1, 32, 64);
    am2 += __shfl_xor(am2, 32, 64);
    am3 += __shfl_xor(am3, 32, 64);
    av0 += __shfl_xor(av0, 32, 64);
    av1 += __shfl_xor(av1, 32, 64);
    av2 += __shfl_xor(av2, 32, 64);
    av3 += __shfl_xor(av3, 32, 64);

    if (half == 0) {
        float k1 = norm1[d], k2 = norm2[d];
        floatx4 om = {am0 * k1, am1 * k1, am2 * k1, am3 * k1};
        floatx4 ov = {av0 * k2, av1 * k2, av2 * k2, av3 * k2};
        __builtin_nontemporal_store(om, (floatx4*)(out_mean + (size_t)d * 128 + j * 4));
        __builtin_nontemporal_store(ov, (floatx4*)(out_var + (size_t)d * 128 + j * 4));
    }
}

extern "C" void kernel_launch(void* const* d_in, const int* in_sizes, int n_in,
                              void* d_out, int out_size, void* d_ws, size_t ws_size,
                              hipStream_t stream) {
    const float* feat = (const float*)d_in[0];
    const float* Wm = (const float*)d_in[1];
    const float* Wv = (const float*)d_in[2];
    const int* src = (const int*)d_in[3];
    const int* dst = (const int*)d_in[4];
    float* out = (float*)d_out;

    const int N = N_NODES;
    const int E = N_EDGES;

    char* wsp = (char*)d_ws;
    auto carve = [&](size_t bytes) {
        char* p = wsp;
        wsp += (bytes + 255) & ~(size_t)255;
        return p;
    };
    f16* msg = (f16*)carve((size_t)N * 256 * sizeof(f16));   // (m,v) pairs, 51.2 MB
    f16* Bt = (f16*)carve((size_t)256 * 256 * sizeof(f16));  // 128 KB
    int* srcs_sorted = (int*)carve((size_t)E * 4);
    int* rank = (int*)carve((size_t)E * 4);
    int* deg = (int*)carve((size_t)N * 4);
    int* row_start = (int*)carve((size_t)(N + 1) * 4);
    float* norm1 = (float*)carve((size_t)N * 4);
    float* norm2 = (float*)carve((size_t)N * 4);
    int* partial = (int*)carve(128 * 4);

    hipMemsetAsync(deg, 0, (size_t)N * 4, stream);

    count_convB_kernel<<<CNT_BLOCKS + 256, 256, 0, stream>>>(dst, E, deg, rank, Wm, Wv, Bt);
    scan_partial_kernel<<<SCAN_BLOCKS, 256, 0, stream>>>(deg, N, partial);
    scan_top_kernel<<<1, 128, 0, stream>>>(partial, SCAN_BLOCKS, row_start, N);
    scan_final_kernel<<<SCAN_BLOCKS, 256, 0, stream>>>(deg, N, partial, row_start, norm1, norm2);
    proj_scatter_kernel<<<PROJ_BLOCKS + SCAT_BLOCKS, 256, 0, stream>>>(
        feat, Bt, norm1, norm2, msg, src, dst, rank, row_start, E, srcs_sorted);
    agg_kernel<<<N / 4, 256, 0, stream>>>(row_start, srcs_sorted, msg, norm1, norm2,
                                          out, out + (size_t)N * OUTF);
}